// Round 3
// baseline (36303.522 us; speedup 1.0000x reference)
//
#include <hip/hip_runtime.h>

// Pendulum 3-layer LSTM (H=128), B=256 rows, 1024 sequential steps.
// Head collapsed to y = weff . h3 + beff (exact, fp32 precompute).
// Persistent kernel: 128 blocks x 512 threads, 2 rows/block.
// Thread = (row r, unit idx, K-half q). Weights fp16, packed [i][u] with
// u = idx*2+q so wave loads are contiguous 1KB dwordx4.
// Ring prefetch depth 4 (consume-then-refill: fixes round-2 aliasing bug).
// 3 barriers/step; partial-gate reduce via shfl_xor(.,1) in-wave.

typedef _Float16 f16;
typedef _Float16 f16x2 __attribute__((ext_vector_type(2)));
typedef unsigned int u32;

#define T_IN 512
#define T_TOT 1024
#define NROW 2
#define NBLK 128

__device__ __forceinline__ f16x2 u2h(u32 u) { return __builtin_bit_cast(f16x2, u); }

__device__ __forceinline__ float fdot2f(f16x2 a, f16x2 b, float c) {
#if __has_builtin(__builtin_amdgcn_fdot2)
  return __builtin_amdgcn_fdot2(a, b, c, false);
#else
  return c + (float)a[0] * (float)b[0] + (float)a[1] * (float)b[1];
#endif
}

__device__ __forceinline__ float frcp(float x) {
#if __has_builtin(__builtin_amdgcn_rcpf)
  return __builtin_amdgcn_rcpf(x);
#else
  return 1.f / x;
#endif
}
__device__ __forceinline__ float fsigm(float x) { return frcp(1.f + __expf(-x)); }
__device__ __forceinline__ float ftanh(float x) { return 1.f - 2.f * frcp(1.f + __expf(2.f * x)); }

// ---- weight packing -------------------------------------------------------
// dst u32[(i*256 + u)*4 + g] = half2{ W[g*128+idx][2p], W[g*128+idx][2p+1] }
// where u = idx*2+q, p = q*(P/2) + i.  p<Pa -> cols of A, else cols of Bm.
__global__ void pack_cat(u32* dst, const float* A, const float* Bm, int Pa, int P) {
  int tid = blockIdx.x * 256 + threadIdx.x;
  if (tid >= P * 512) return;
  int g = tid & 3;
  int u = (tid >> 2) & 255;
  int i = tid >> 10;
  int Ph = P >> 1;
  int idx = u >> 1, q = u & 1;
  int p = q * Ph + i;
  int j = g * 128 + idx;
  const float* src;
  int k;
  if (p < Pa) { src = A; k = 2 * p; } else { src = Bm; k = 2 * (p - Pa); }
  union { f16 h[2]; u32 u; } cv;
  cv.h[0] = (f16)src[j * 128 + k];
  cv.h[1] = (f16)src[j * 128 + k + 1];
  dst[tid] = cv.u;
}

__global__ void bias_add3(float* d1, float* d2, float* d3,
                          const float* a1, const float* b1,
                          const float* a2, const float* b2,
                          const float* a3, const float* b3) {
  int tid = blockIdx.x * 256 + threadIdx.x;
  if (tid < 512) d1[tid] = a1[tid] + b1[tid];
  else if (tid < 1024) d2[tid - 512] = a2[tid - 512] + b2[tid - 512];
  else if (tid < 1536) d3[tid - 1024] = a3[tid - 1024] + b3[tid - 1024];
}

// Head collapse: y = h3 . weff + beff  (exact linear algebra, fp32)
__global__ void head_fold(float* weff, float* beff,
                          const float* lin_w, const float* out_w,
                          const float* Wv, const float* bv,
                          const float* out_b, const float* lin_b) {
  __shared__ float wlo[128];
  __shared__ float pr[128];
  int j = threadIdx.x;
  float s = 0.f;
  for (int k = 0; k < 128; ++k) s += lin_w[k] * out_w[k * 128 + j];
  wlo[j] = s;
  __syncthreads();
  float t = 0.f;
  for (int k = 0; k < 128; ++k) t += wlo[k] * Wv[k * 128 + j];
  weff[j] = t;
  pr[j] = s * bv[j] + lin_w[j] * out_b[j];
  __syncthreads();
  if (j == 0) {
    float b = lin_b[0];
    for (int k = 0; k < 128; ++k) b += pr[k];
    beff[0] = b;
  }
}

// ---- pipelined stage dot --------------------------------------------------
// NCH chunks of 8 pairs each. W indexed [i][u] (uint4 = 4 gates), i=c*8+qq.
// hp: this thread's contiguous h source (16 halves per chunk).
// Ring depth 4, CONSUME buffer before refilling it (round-2 bug fix).
template <int NCH>
__device__ __forceinline__ void stage_dot(const uint4* __restrict__ W,
                                          const f16* __restrict__ hp,
                                          int u, float (&a)[4]) {
  uint4 w[4][8];
  u32 hcc[4][8];

  auto ldw = [&](int c, int buf) {
    const uint4* Wp = W + c * 8 * 256 + u;
#pragma unroll
    for (int qq = 0; qq < 8; ++qq) w[buf][qq] = Wp[qq * 256];
  };
  auto ldh = [&](int c, int buf) {
    uint4 h01 = *reinterpret_cast<const uint4*>(hp + 16 * c);
    uint4 h23 = *reinterpret_cast<const uint4*>(hp + 16 * c + 8);
    hcc[buf][0] = h01.x; hcc[buf][1] = h01.y; hcc[buf][2] = h01.z; hcc[buf][3] = h01.w;
    hcc[buf][4] = h23.x; hcc[buf][5] = h23.y; hcc[buf][6] = h23.z; hcc[buf][7] = h23.w;
  };

#pragma unroll
  for (int c = 0; c < 4 && c < NCH; ++c) { ldw(c, c); ldh(c, c); }
#pragma unroll
  for (int c = 0; c < NCH; ++c) {
    // consume buffer c&3 (holds chunk c)
#pragma unroll
    for (int qq = 0; qq < 8; ++qq) {
      uint4 wq = w[c & 3][qq];
      f16x2 hh = u2h(hcc[c & 3][qq]);
      a[0] = fdot2f(u2h(wq.x), hh, a[0]);
      a[1] = fdot2f(u2h(wq.y), hh, a[1]);
      a[2] = fdot2f(u2h(wq.z), hh, a[2]);
      a[3] = fdot2f(u2h(wq.w), hh, a[3]);
    }
    // refill the just-freed buffer with chunk c+4
    if (c + 4 < NCH) { ldw(c + 4, c & 3); ldh(c + 4, c & 3); }
  }
}

// ---- main persistent kernel ----------------------------------------------
__global__ __launch_bounds__(512, 2) void pendulum_persist(
    const float* __restrict__ input, const float* __restrict__ wih1,
    const float* __restrict__ B1, const float* __restrict__ B2,
    const float* __restrict__ B3, const uint4* __restrict__ WT1,
    const uint4* __restrict__ WT2, const uint4* __restrict__ WT3,
    const float* __restrict__ weff, const float* __restrict__ beff,
    float* __restrict__ out) {
  __shared__ __align__(16) f16 hbuf[2][NROW][384];
  __shared__ float redp[8];

  const int t = threadIdx.x;
  const int r = t >> 8;    // row within block (0..1)
  const int u = t & 255;
  const int idx = u >> 1;  // hidden unit
  const int q = u & 1;     // K-half
  const int row = blockIdx.x * NROW + r;

  float b1g[4], b2g[4], b3g[4], w1g[4];
#pragma unroll
  for (int g = 0; g < 4; ++g) {
    b1g[g] = B1[g * 128 + idx];
    b2g[g] = B2[g * 128 + idx];
    b3g[g] = B3[g * 128 + idx];
    w1g[g] = wih1[g * 128 + idx];
  }
  const float weffr = weff[idx];
  const float beffv = beff[0];
  float c1 = 0.f, c2 = 0.f, c3 = 0.f;
  float xreg = 0.f;

  for (int e = t; e < 2 * NROW * 384; e += 512) ((f16*)hbuf)[e] = (f16)0.f;
  __syncthreads();

  int s = 0;
  for (int step = 0; step < T_TOT; ++step) {
    int xi = (step < T_IN) ? step : (T_IN - 1);
    float xl = input[row * T_IN + xi];
    float xv = (step < T_IN) ? xl : xreg;

    const f16* hold = &hbuf[s][r][0];
    f16* hnew = &hbuf[s ^ 1][r][0];
    float a[4];

    // ---- layer 1: gates = b1 + x*wih1 + h1_old @ Whh1^T
#pragma unroll
    for (int g = 0; g < 4; ++g) a[g] = 0.f;
    stage_dot<4>(WT1, hold + q * 64, u, a);
#pragma unroll
    for (int g = 0; g < 4; ++g) a[g] += __shfl_xor(a[g], 1, 64);
    if (q == 0) {
      float ig = fsigm(a[0] + b1g[0] + xv * w1g[0]);
      float fg = fsigm(a[1] + b1g[1] + xv * w1g[1]);
      float gg = ftanh(a[2] + b1g[2] + xv * w1g[2]);
      float og = fsigm(a[3] + b1g[3] + xv * w1g[3]);
      c1 = fg * c1 + ig * gg;
      hnew[idx] = (f16)(og * ftanh(c1));
    }
    __syncthreads(); // h1_new visible

    // ---- layer 2: [h1_new | h2_old]
#pragma unroll
    for (int g = 0; g < 4; ++g) a[g] = 0.f;
    stage_dot<8>(WT2, q ? (hold + 128) : hnew, u, a);
#pragma unroll
    for (int g = 0; g < 4; ++g) a[g] += __shfl_xor(a[g], 1, 64);
    if (q == 0) {
      float ig = fsigm(a[0] + b2g[0]);
      float fg = fsigm(a[1] + b2g[1]);
      float gg = ftanh(a[2] + b2g[2]);
      float og = fsigm(a[3] + b2g[3]);
      c2 = fg * c2 + ig * gg;
      hnew[128 + idx] = (f16)(og * ftanh(c2));
    }
    __syncthreads(); // h2_new visible

    // ---- layer 3: [h2_new | h3_old], fused head partial
#pragma unroll
    for (int g = 0; g < 4; ++g) a[g] = 0.f;
    stage_dot<8>(WT3, q ? (hold + 256) : (hnew + 128), u, a);
#pragma unroll
    for (int g = 0; g < 4; ++g) a[g] += __shfl_xor(a[g], 1, 64);
    float part = 0.f;
    if (q == 0) {
      float ig = fsigm(a[0] + b3g[0]);
      float fg = fsigm(a[1] + b3g[1]);
      float gg = ftanh(a[2] + b3g[2]);
      float og = fsigm(a[3] + b3g[3]);
      c3 = fg * c3 + ig * gg;
      float h3f = og * ftanh(c3);
      hnew[256 + idx] = (f16)h3f;
      part = weffr * h3f;
    }
#pragma unroll
    for (int k = 32; k; k >>= 1) part += __shfl_xor(part, k, 64);
    if ((t & 63) == 0) redp[t >> 6] = part;
    __syncthreads(); // h3_new + partials visible

    float o = redp[r * 4 + 0] + redp[r * 4 + 1] + redp[r * 4 + 2] +
              redp[r * 4 + 3] + beffv;
    if (u == 0) out[row * T_TOT + step] = o;
    xreg = o;
    s ^= 1;
  }
}

// ---- launch ---------------------------------------------------------------
extern "C" void kernel_launch(void* const* d_in, const int* in_sizes, int n_in,
                              void* d_out, int out_size, void* d_ws, size_t ws_size,
                              hipStream_t stream) {
  const float* input = (const float*)d_in[0];
  const float* Wih1 = (const float*)d_in[2];
  const float* Whh1 = (const float*)d_in[3];
  const float* bih1 = (const float*)d_in[4];
  const float* bhh1 = (const float*)d_in[5];
  const float* Wih2 = (const float*)d_in[6];
  const float* Whh2 = (const float*)d_in[7];
  const float* bih2 = (const float*)d_in[8];
  const float* bhh2 = (const float*)d_in[9];
  const float* Wih3 = (const float*)d_in[10];
  const float* Whh3 = (const float*)d_in[11];
  const float* bih3 = (const float*)d_in[12];
  const float* bhh3 = (const float*)d_in[13];
  const float* in_proj_w = (const float*)d_in[14];
  const float* in_proj_b = (const float*)d_in[15];
  const float* out_w = (const float*)d_in[16];
  const float* out_b = (const float*)d_in[17];
  const float* lin_w = (const float*)d_in[18];
  const float* lin_b = (const float*)d_in[19];

  char* ws = (char*)d_ws;
  u32* WT1 = (u32*)(ws + (0 << 10));    // 128 KB
  u32* WT2 = (u32*)(ws + (128 << 10));  // 256 KB
  u32* WT3 = (u32*)(ws + (384 << 10));  // 256 KB
  float* B1 = (float*)(ws + (640 << 10));
  float* B2 = (float*)(ws + (642 << 10));
  float* B3 = (float*)(ws + (644 << 10));
  float* weff = (float*)(ws + (646 << 10));
  float* beff = (float*)(ws + (647 << 10));

  pack_cat<<<128, 256, 0, stream>>>(WT1, Whh1, Whh1, 64, 64);
  pack_cat<<<256, 256, 0, stream>>>(WT2, Wih2, Whh2, 64, 128);
  pack_cat<<<256, 256, 0, stream>>>(WT3, Wih3, Whh3, 64, 128);
  bias_add3<<<6, 256, 0, stream>>>(B1, B2, B3, bih1, bhh1, bih2, bhh2, bih3, bhh3);
  head_fold<<<1, 128, 0, stream>>>(weff, beff, lin_w, out_w,
                                   in_proj_w + 2 * 128 * 128, in_proj_b + 256,
                                   out_b, lin_b);

  pendulum_persist<<<NBLK, 512, 0, stream>>>(
      input, Wih1, B1, B2, B3, (const uint4*)WT1, (const uint4*)WT2,
      (const uint4*)WT3, weff, beff, (float*)d_out);
}

// Round 4
// 12762.383 us; speedup vs baseline: 2.8446x; 2.8446x over previous
//
#include <hip/hip_runtime.h>

// Pendulum 3-layer LSTM (H=128), B=256 rows, 1024 sequential steps.
// Head collapsed to y = weff.h3 + beff (exact fp32 precompute).
// 128 blocks x 512 threads, 2 rows/block. Thread = (idx in 128, kq in 4).
// L1+L2 weights register-resident (192 VGPRs/thread, loaded once).
// L3 weights (256KB) streamed per step via global_load_lds into a 6x16KB
// LDS ring, counted vmcnt + raw s_barrier (5 chunks in flight).

typedef _Float16 f16;
typedef _Float16 f16x2 __attribute__((ext_vector_type(2)));
typedef unsigned int u32;

#define T_IN 512
#define T_TOT 1024
#define NBLK 128

__device__ __forceinline__ f16x2 u2h(u32 u) { return __builtin_bit_cast(f16x2, u); }

__device__ __forceinline__ float fdot2f(f16x2 a, f16x2 b, float c) {
#if __has_builtin(__builtin_amdgcn_fdot2)
  return __builtin_amdgcn_fdot2(a, b, c, false);
#else
  return c + (float)a[0] * (float)b[0] + (float)a[1] * (float)b[1];
#endif
}

__device__ __forceinline__ float frcp(float x) {
#if __has_builtin(__builtin_amdgcn_rcpf)
  return __builtin_amdgcn_rcpf(x);
#else
  return 1.f / x;
#endif
}
__device__ __forceinline__ float fsigm(float x) { return frcp(1.f + __expf(-x)); }
__device__ __forceinline__ float ftanh(float x) { return 1.f - 2.f * frcp(1.f + __expf(2.f * x)); }

__device__ __forceinline__ void gl_lds16(const void* g, void* l) {
  __builtin_amdgcn_global_load_lds((const __attribute__((address_space(1))) u32*)g,
                                   (__attribute__((address_space(3))) u32*)l, 16, 0, 0);
}

__device__ __forceinline__ float lstm_do(const float* a, float4 b, float x0, float x1,
                                         float x2, float x3, float& c) {
  float ig = fsigm(a[0] + b.x + x0);
  float fg = fsigm(a[1] + b.y + x1);
  float gg = ftanh(a[2] + b.z + x2);
  float og = fsigm(a[3] + b.w + x3);
  c = fg * c + ig * gg;
  return og * ftanh(c);
}

#define DOT4(acc, w, hv)                         \
  do {                                           \
    f16x2 _h = u2h(hv);                          \
    acc[0] = fdot2f(u2h((w).x), _h, acc[0]);     \
    acc[1] = fdot2f(u2h((w).y), _h, acc[1]);     \
    acc[2] = fdot2f(u2h((w).z), _h, acc[2]);     \
    acc[3] = fdot2f(u2h((w).w), _h, acc[3]);     \
  } while (0)

// ---- weight packing (round-1 verified layout: [pair p][idx][gate] u32) ----
__global__ void pack_cat(u32* dst, const float* A, const float* Bm, int Pa, int P) {
  int tid = blockIdx.x * 256 + threadIdx.x;
  if (tid >= P * 512) return;
  int g = tid & 3;
  int idx = (tid >> 2) & 127;
  int p = tid >> 9;
  int j = g * 128 + idx;
  const float* src;
  int k;
  if (p < Pa) { src = A; k = 2 * p; } else { src = Bm; k = 2 * (p - Pa); }
  union { f16 h[2]; u32 u; } cv;
  cv.h[0] = (f16)src[j * 128 + k];
  cv.h[1] = (f16)src[j * 128 + k + 1];
  dst[tid] = cv.u;
}

// cons[idx*16 + gg*4 + g]: gg=0:b1, 1:b2, 2:b3, 3:wih1 (per-gate)
__global__ void prep_cons(float* cons, const float* a1, const float* b1,
                          const float* a2, const float* b2,
                          const float* a3, const float* b3, const float* wih1) {
  int tid = blockIdx.x * 256 + threadIdx.x;
  if (tid >= 2048) return;
  int idx = tid >> 4, e = tid & 15, gg = e >> 2, g = e & 3;
  int j = g * 128 + idx;
  float v;
  if (gg == 0) v = a1[j] + b1[j];
  else if (gg == 1) v = a2[j] + b2[j];
  else if (gg == 2) v = a3[j] + b3[j];
  else v = wih1[j];
  cons[tid] = v;
}

// Head collapse: y = h3 . weff + beff (exact fp32)
__global__ void head_fold(float* weff, float* beff,
                          const float* lin_w, const float* out_w,
                          const float* Wv, const float* bv,
                          const float* out_b, const float* lin_b) {
  __shared__ float wlo[128];
  __shared__ float pr[128];
  int j = threadIdx.x;
  float s = 0.f;
  for (int k = 0; k < 128; ++k) s += lin_w[k] * out_w[k * 128 + j];
  wlo[j] = s;
  __syncthreads();
  float t = 0.f;
  for (int k = 0; k < 128; ++k) t += wlo[k] * Wv[k * 128 + j];
  weff[j] = t;
  pr[j] = s * bv[j] + lin_w[j] * out_b[j];
  __syncthreads();
  if (j == 0) {
    float b = lin_b[0];
    for (int k = 0; k < 128; ++k) b += pr[k];
    beff[0] = b;
  }
}

// ---- main persistent kernel ----------------------------------------------
__global__ __launch_bounds__(512, 2) void pendulum_persist(
    const float* __restrict__ input, const uint4* __restrict__ WT1,
    const uint4* __restrict__ WT2, const uint4* __restrict__ WT3,
    const float* __restrict__ consG, const float* __restrict__ weff,
    const float* __restrict__ beff, float* __restrict__ out) {
  __shared__ __align__(16) uint4 stg[6][1024];   // 96 KB: 6 bufs x (8 pairs x 128 idx)
  __shared__ __align__(16) f16 hbuf[2][2][384];  // 3 KB: [step parity][row][h1|h2|h3]
  __shared__ __align__(16) float consL[2048];    // 8 KB
  __shared__ float redp[2][8];

  const int t = threadIdx.x;
  const int idx = t >> 2;  // hidden unit
  const int kq = t & 3;    // K-quarter
  const int row0 = blockIdx.x * 2;
  const int row1 = row0 + 1;

  for (int e = t; e < 2048; e += 512) consL[e] = consG[e];
  for (int e = t; e < 1536; e += 512) ((f16*)hbuf)[e] = (f16)0.f;

  // resident weights: L1 pairs kq*16+j, L2 pairs kq*32+j
  uint4 w1r[16];
#pragma unroll
  for (int j = 0; j < 16; ++j) w1r[j] = WT1[(kq * 16 + j) * 128 + idx];
  uint4 w2r[32];
#pragma unroll
  for (int j = 0; j < 32; ++j) w2r[j] = WT2[(kq * 32 + j) * 128 + idx];

  const float weffr = weff[idx];
  const float beffv = beff[0];
  float c1a = 0.f, c1b = 0.f, c2a = 0.f, c2b = 0.f, c3a = 0.f, c3b = 0.f;
  float y0 = 0.f, y1 = 0.f;
  __syncthreads();

  int s = 0;
  for (int step = 0; step < T_TOT; ++step) {
    int xi = (step < T_IN) ? step : (T_IN - 1);
    float xl0 = input[row0 * T_IN + xi];
    float xl1 = input[row1 * T_IN + xi];
    __builtin_amdgcn_sched_barrier(0);
    // prologue: stage L3 chunks 0..4 (5 in flight, 2 loads each)
#pragma unroll
    for (int n = 0; n < 5; ++n) {
#pragma unroll
      for (int i = 0; i < 2; ++i)
        gl_lds16(WT3 + n * 1024 + i * 512 + t, &stg[n][i * 512 + (t & 448)]);
    }
    __builtin_amdgcn_sched_barrier(0);

    float xv0 = (step < T_IN) ? xl0 : y0;
    float xv1 = (step < T_IN) ? xl1 : y1;

    const f16* h0 = &hbuf[s][0][0];
    const f16* h1o = &hbuf[s][1][0];
    f16* n0 = &hbuf[s ^ 1][0][0];
    f16* n1 = &hbuf[s ^ 1][1][0];

    // ---- layer 1 (resident): K = h1_old
    float a0[4] = {0.f, 0.f, 0.f, 0.f}, a1[4] = {0.f, 0.f, 0.f, 0.f};
    {
      const uint4* H0 = (const uint4*)(h0 + 32 * kq);
      const uint4* H1 = (const uint4*)(h1o + 32 * kq);
#pragma unroll
      for (int q4 = 0; q4 < 4; ++q4) {
        uint4 v0 = H0[q4], v1 = H1[q4];
        u32 e0[4] = {v0.x, v0.y, v0.z, v0.w};
        u32 e1[4] = {v1.x, v1.y, v1.z, v1.w};
#pragma unroll
        for (int e = 0; e < 4; ++e) {
          uint4 w = w1r[q4 * 4 + e];
          DOT4(a0, w, e0[e]);
          DOT4(a1, w, e1[e]);
        }
      }
    }
#pragma unroll
    for (int g = 0; g < 4; ++g) {
      a0[g] += __shfl_xor(a0[g], 1, 64); a0[g] += __shfl_xor(a0[g], 2, 64);
      a1[g] += __shfl_xor(a1[g], 1, 64); a1[g] += __shfl_xor(a1[g], 2, 64);
    }
    {
      float4 b1 = *(const float4*)&consL[idx * 16 + 0];
      float4 wx = *(const float4*)&consL[idx * 16 + 12];
      float hA = lstm_do(a0, b1, xv0 * wx.x, xv0 * wx.y, xv0 * wx.z, xv0 * wx.w, c1a);
      float hB = lstm_do(a1, b1, xv1 * wx.x, xv1 * wx.y, xv1 * wx.z, xv1 * wx.w, c1b);
      if (kq == 0) { n0[idx] = (f16)hA; n1[idx] = (f16)hB; }
    }
    __syncthreads();  // h1_new visible

    // ---- layer 2 (resident): K = [h1_new | h2_old]
    float b0[4] = {0.f, 0.f, 0.f, 0.f}, b1a[4] = {0.f, 0.f, 0.f, 0.f};
    {
      const f16* hb0 = (kq < 2) ? (n0 + 64 * kq) : (h0 + 128 + 64 * (kq - 2));
      const f16* hb1 = (kq < 2) ? (n1 + 64 * kq) : (h1o + 128 + 64 * (kq - 2));
      const uint4* H0 = (const uint4*)hb0;
      const uint4* H1 = (const uint4*)hb1;
#pragma unroll
      for (int q8 = 0; q8 < 8; ++q8) {
        uint4 v0 = H0[q8], v1 = H1[q8];
        u32 e0[4] = {v0.x, v0.y, v0.z, v0.w};
        u32 e1[4] = {v1.x, v1.y, v1.z, v1.w};
#pragma unroll
        for (int e = 0; e < 4; ++e) {
          uint4 w = w2r[q8 * 4 + e];
          DOT4(b0, w, e0[e]);
          DOT4(b1a, w, e1[e]);
        }
      }
    }
#pragma unroll
    for (int g = 0; g < 4; ++g) {
      b0[g] += __shfl_xor(b0[g], 1, 64); b0[g] += __shfl_xor(b0[g], 2, 64);
      b1a[g] += __shfl_xor(b1a[g], 1, 64); b1a[g] += __shfl_xor(b1a[g], 2, 64);
    }
    {
      float4 bb = *(const float4*)&consL[idx * 16 + 4];
      float hA = lstm_do(b0, bb, 0.f, 0.f, 0.f, 0.f, c2a);
      float hB = lstm_do(b1a, bb, 0.f, 0.f, 0.f, 0.f, c2b);
      if (kq == 0) { n0[128 + idx] = (f16)hA; n1[128 + idx] = (f16)hB; }
    }
    __syncthreads();  // h2_new visible (also drains stage vmcnt -- harmless)

    // ---- layer 3 (streamed): K = [h2_new | h3_old], 16 chunks of 8 pairs
    float g0[4] = {0.f, 0.f, 0.f, 0.f}, g1[4] = {0.f, 0.f, 0.f, 0.f};
    const u32* nn0 = (const u32*)n0;
    const u32* nn1 = (const u32*)n1;
    const u32* oo0 = (const u32*)h0;
    const u32* oo1 = (const u32*)h1o;
#pragma unroll
    for (int c = 0; c < 16; ++c) {
      if (c < 12)       asm volatile("s_waitcnt vmcnt(8)" ::: "memory");
      else if (c == 12) asm volatile("s_waitcnt vmcnt(6)" ::: "memory");
      else if (c == 13) asm volatile("s_waitcnt vmcnt(4)" ::: "memory");
      else if (c == 14) asm volatile("s_waitcnt vmcnt(2)" ::: "memory");
      else              asm volatile("s_waitcnt vmcnt(0)" ::: "memory");
      __builtin_amdgcn_s_barrier();
      __builtin_amdgcn_sched_barrier(0);
#pragma unroll
      for (int j = 0; j < 2; ++j) {
        int pp = 2 * kq + j;
        uint4 w = stg[c % 6][pp * 128 + idx];
        u32 hv0, hv1;
        if (c < 8) { hv0 = nn0[64 + c * 8 + pp]; hv1 = nn1[64 + c * 8 + pp]; }
        else       { hv0 = oo0[64 + c * 8 + pp]; hv1 = oo1[64 + c * 8 + pp]; }
        DOT4(g0, w, hv0);
        DOT4(g1, w, hv1);
      }
      if (c + 5 < 16) {
        const int n = c + 5;
#pragma unroll
        for (int i = 0; i < 2; ++i)
          gl_lds16(WT3 + n * 1024 + i * 512 + t, &stg[n % 6][i * 512 + (t & 448)]);
      }
    }
#pragma unroll
    for (int g = 0; g < 4; ++g) {
      g0[g] += __shfl_xor(g0[g], 1, 64); g0[g] += __shfl_xor(g0[g], 2, 64);
      g1[g] += __shfl_xor(g1[g], 1, 64); g1[g] += __shfl_xor(g1[g], 2, 64);
    }
    float4 b3 = *(const float4*)&consL[idx * 16 + 8];
    float h3A = lstm_do(g0, b3, 0.f, 0.f, 0.f, 0.f, c3a);
    float h3B = lstm_do(g1, b3, 0.f, 0.f, 0.f, 0.f, c3b);
    if (kq == 0) { n0[256 + idx] = (f16)h3A; n1[256 + idx] = (f16)h3B; }

    // ---- head: y = weff.h3 + beff
    float p0 = (kq == 0) ? weffr * h3A : 0.f;
    float p1 = (kq == 0) ? weffr * h3B : 0.f;
#pragma unroll
    for (int k = 1; k < 64; k <<= 1) {
      p0 += __shfl_xor(p0, k, 64);
      p1 += __shfl_xor(p1, k, 64);
    }
    if ((t & 63) == 0) { redp[0][t >> 6] = p0; redp[1][t >> 6] = p1; }
    __syncthreads();  // partials + h3_new visible
    y0 = beffv; y1 = beffv;
#pragma unroll
    for (int w8 = 0; w8 < 8; ++w8) { y0 += redp[0][w8]; y1 += redp[1][w8]; }
    if (t == 0) out[row0 * T_TOT + step] = y0;
    else if (t == 1) out[row1 * T_TOT + step] = y1;
    s ^= 1;
  }
}

// ---- launch ---------------------------------------------------------------
extern "C" void kernel_launch(void* const* d_in, const int* in_sizes, int n_in,
                              void* d_out, int out_size, void* d_ws, size_t ws_size,
                              hipStream_t stream) {
  const float* input = (const float*)d_in[0];
  const float* Wih1 = (const float*)d_in[2];
  const float* Whh1 = (const float*)d_in[3];
  const float* bih1 = (const float*)d_in[4];
  const float* bhh1 = (const float*)d_in[5];
  const float* Wih2 = (const float*)d_in[6];
  const float* Whh2 = (const float*)d_in[7];
  const float* bih2 = (const float*)d_in[8];
  const float* bhh2 = (const float*)d_in[9];
  const float* Wih3 = (const float*)d_in[10];
  const float* Whh3 = (const float*)d_in[11];
  const float* bih3 = (const float*)d_in[12];
  const float* bhh3 = (const float*)d_in[13];
  const float* in_proj_w = (const float*)d_in[14];
  const float* in_proj_b = (const float*)d_in[15];
  const float* out_w = (const float*)d_in[16];
  const float* out_b = (const float*)d_in[17];
  const float* lin_w = (const float*)d_in[18];
  const float* lin_b = (const float*)d_in[19];

  char* ws = (char*)d_ws;
  u32* WT1 = (u32*)(ws + (0 << 10));     // 128 KB
  u32* WT2 = (u32*)(ws + (128 << 10));   // 256 KB
  u32* WT3 = (u32*)(ws + (384 << 10));   // 256 KB
  float* consG = (float*)(ws + (640 << 10));  // 8 KB
  float* weff = (float*)(ws + (649 << 10));
  float* beff = (float*)(ws + (650 << 10));

  pack_cat<<<128, 256, 0, stream>>>(WT1, Whh1, Whh1, 64, 64);
  pack_cat<<<256, 256, 0, stream>>>(WT2, Wih2, Whh2, 64, 128);
  pack_cat<<<256, 256, 0, stream>>>(WT3, Wih3, Whh3, 64, 128);
  prep_cons<<<8, 256, 0, stream>>>(consG, bih1, bhh1, bih2, bhh2, bih3, bhh3, Wih1);
  head_fold<<<1, 128, 0, stream>>>(weff, beff, lin_w, out_w,
                                   in_proj_w + 2 * 128 * 128, in_proj_b + 256,
                                   out_b, lin_b);

  pendulum_persist<<<NBLK, 512, 0, stream>>>(
      input, (const uint4*)WT1, (const uint4*)WT2, (const uint4*)WT3,
      consG, weff, beff, (float*)d_out);
}

// Round 5
// 10174.943 us; speedup vs baseline: 3.5679x; 1.2543x over previous
//
#include <hip/hip_runtime.h>

// Pendulum 3-layer LSTM (H=128), B=256 rows, 1024 sequential steps.
// Head collapsed to y = weff.h3 + beff (exact fp32 precompute).
// 128 blocks x 512 threads, 2 rows/block. Thread = (idx in 128, kq in 4).
//   L1 weights (128KB): LDS-resident, bank-swizzled, loaded once.
//   L2 weights (256KB): register-resident (32 uint4 = 128 VGPRs).
//   L3 weights (256KB): streamed global->VGPR via persistent 8-slot ring;
//     Whh3*h3_old half interleaved with L2 dots, Wih3*h2_new half interleaved
//     with the NEXT step's L1 dots (cross-step software pipeline).
// 3 barriers/step, raw s_barrier + lgkmcnt(0) only (ring survives barriers).

typedef _Float16 f16;
typedef _Float16 f16x2 __attribute__((ext_vector_type(2)));
typedef unsigned int u32;

#define T_IN 512
#define T_TOT 1024
#define NBLK 128

__device__ __forceinline__ f16x2 u2h(u32 u) { return __builtin_bit_cast(f16x2, u); }

__device__ __forceinline__ float fdot2f(f16x2 a, f16x2 b, float c) {
#if __has_builtin(__builtin_amdgcn_fdot2)
  return __builtin_amdgcn_fdot2(a, b, c, false);
#else
  return c + (float)a[0] * (float)b[0] + (float)a[1] * (float)b[1];
#endif
}

__device__ __forceinline__ float frcp(float x) {
#if __has_builtin(__builtin_amdgcn_rcpf)
  return __builtin_amdgcn_rcpf(x);
#else
  return 1.f / x;
#endif
}
__device__ __forceinline__ float fsigm(float x) { return frcp(1.f + __expf(-x)); }
__device__ __forceinline__ float ftanh(float x) { return 1.f - 2.f * frcp(1.f + __expf(2.f * x)); }

#define DOT4(acc, w, hv)                     \
  do {                                       \
    f16x2 _h = u2h(hv);                      \
    acc[0] = fdot2f(u2h((w).x), _h, acc[0]); \
    acc[1] = fdot2f(u2h((w).y), _h, acc[1]); \
    acc[2] = fdot2f(u2h((w).z), _h, acc[2]); \
    acc[3] = fdot2f(u2h((w).w), _h, acc[3]); \
  } while (0)

// ---- weight packing -------------------------------------------------------
// Std layout: uint4 at [pair p][idx], u32 slot g: half2{W[g*128+idx][2p],[2p+1]}
__global__ void pack_cat(u32* dst, const float* A, const float* Bm, int Pa, int P) {
  int tid = blockIdx.x * 256 + threadIdx.x;
  if (tid >= P * 512) return;
  int g = tid & 3;
  int idx = (tid >> 2) & 127;
  int p = tid >> 9;
  int j = g * 128 + idx;
  const float* src;
  int k;
  if (p < Pa) { src = A; k = 2 * p; } else { src = Bm; k = 2 * (p - Pa); }
  union { f16 h[2]; u32 u; } cv;
  cv.h[0] = (f16)src[j * 128 + k];
  cv.h[1] = (f16)src[j * 128 + k + 1];
  dst[tid] = cv.u;
}

// L1 (Whh1 only, 64 pairs), bank-swizzled: slot = p*128 + (idx ^ (2*(p>>4)))
__global__ void pack1(u32* dst, const float* Whh1) {
  int tid = blockIdx.x * 256 + threadIdx.x;
  if (tid >= 64 * 512) return;
  int g = tid & 3;
  int idx = (tid >> 2) & 127;
  int p = tid >> 9;
  int j = g * 128 + idx;
  union { f16 h[2]; u32 u; } cv;
  cv.h[0] = (f16)Whh1[j * 128 + 2 * p];
  cv.h[1] = (f16)Whh1[j * 128 + 2 * p + 1];
  dst[(p * 128 + (idx ^ (2 * (p >> 4)))) * 4 + g] = cv.u;
}

// L3 stream order: uint4 index = i*512 + idx*4 + kq, i = consumption order.
// i<16 (early): p = 64 + kq*16 + i  (Whh3, vs h3_old pair kq*16+i)
// i>=16 (late): p = kq*16 + (i-16)  (Wih3, vs h2_new pair kq*16+(i-16))
__global__ void pack3(u32* dst, const float* Wih3, const float* Whh3) {
  int tid = blockIdx.x * 256 + threadIdx.x;
  if (tid >= 128 * 512) return;
  int g = tid & 3;
  int u4i = tid >> 2;
  int kq = u4i & 3;
  int idx = (u4i >> 2) & 127;
  int i = u4i >> 9;
  int p = (i < 16) ? (64 + kq * 16 + i) : (kq * 16 + (i - 16));
  int j = g * 128 + idx;
  const float* src = (p < 64) ? Wih3 : Whh3;
  int k = (p < 64) ? 2 * p : 2 * (p - 64);
  union { f16 h[2]; u32 u; } cv;
  cv.h[0] = (f16)src[j * 128 + k];
  cv.h[1] = (f16)src[j * 128 + k + 1];
  dst[tid] = cv.u;
}

// consT[gg*512 + g*128 + idx]: gg 0=b1,1=b2,2=b3,3=wih1. [2048+idx]=weff, [2176]=beff.
__global__ void prep_cons(float* cons, const float* a1, const float* b1,
                          const float* a2, const float* b2,
                          const float* a3, const float* b3, const float* wih1) {
  int tid = blockIdx.x * 256 + threadIdx.x;
  if (tid >= 2048) return;
  int gg = tid >> 9, g = (tid >> 7) & 3, idx = tid & 127;
  int j = g * 128 + idx;
  float v;
  if (gg == 0) v = a1[j] + b1[j];
  else if (gg == 1) v = a2[j] + b2[j];
  else if (gg == 2) v = a3[j] + b3[j];
  else v = wih1[j];
  cons[tid] = v;
}

__global__ void head_fold(float* cons, const float* lin_w, const float* out_w,
                          const float* Wv, const float* bv,
                          const float* out_b, const float* lin_b) {
  __shared__ float wlo[128];
  __shared__ float pr[128];
  int j = threadIdx.x;
  float s = 0.f;
  for (int k = 0; k < 128; ++k) s += lin_w[k] * out_w[k * 128 + j];
  wlo[j] = s;
  __syncthreads();
  float t = 0.f;
  for (int k = 0; k < 128; ++k) t += wlo[k] * Wv[k * 128 + j];
  cons[2048 + j] = t;
  pr[j] = s * bv[j] + lin_w[j] * out_b[j];
  __syncthreads();
  if (j == 0) {
    float b = lin_b[0];
    for (int k = 0; k < 128; ++k) b += pr[k];
    cons[2176] = b;
  }
}

// ---- main persistent kernel ----------------------------------------------
__global__ __launch_bounds__(512, 2) void pendulum_persist(
    const float* __restrict__ input, const uint4* __restrict__ WT1g,
    const uint4* __restrict__ WT2, const uint4* __restrict__ WT3r,
    const float* __restrict__ consG, float* __restrict__ out) {
  __shared__ __align__(16) uint4 w1lds[8192];   // 128 KB, swizzled L1
  __shared__ __align__(16) f16 h1b[2][2][128];  // [parity][row][idx]
  __shared__ __align__(16) f16 h2b[2][2][128];
  __shared__ __align__(16) f16 h3b[2][128];     // [row][idx], single buffer
  __shared__ float consL[2180];
  __shared__ float redp[2][8];

  const int t = threadIdx.x;
  const int idx = t >> 2;
  const int kq = t & 3;
  const int row0 = blockIdx.x * 2, row1 = row0 + 1;

  for (int e = t; e < 8192; e += 512) w1lds[e] = WT1g[e];
  for (int e = t; e < 2177; e += 512) consL[e] = consG[e];
  if (t < 128) {
    h1b[0][0][t] = (f16)0.f; h1b[0][1][t] = (f16)0.f;
    h1b[1][0][t] = (f16)0.f; h1b[1][1][t] = (f16)0.f;
    h2b[0][0][t] = (f16)0.f; h2b[0][1][t] = (f16)0.f;
    h2b[1][0][t] = (f16)0.f; h2b[1][1][t] = (f16)0.f;
    h3b[0][t] = (f16)0.f;    h3b[1][t] = (f16)0.f;
  }

  uint4 w2r[32];
#pragma unroll
  for (int j = 0; j < 32; ++j) w2r[j] = WT2[(kq * 32 + j) * 128 + idx];

  const uint4* W3p = WT3r + t;
  const uint4* w1p = w1lds + kq * 2048 + (idx ^ (2 * kq));

  float c1a = 0.f, c1b = 0.f, c2a = 0.f, c2b = 0.f, c3a = 0.f, c3b = 0.f;
  float y0 = 0.f, y1 = 0.f;
  __syncthreads();
  const float beffv = consL[2176];

  // prologue: step-0 layer1 (h1_old = 0 -> no dots)
  {
    float x0 = input[row0 * T_IN], x1 = input[row1 * T_IN];
    if (kq == 0) {
      float b0 = consL[idx], b1v = consL[128 + idx], b2v = consL[256 + idx],
            b3v = consL[384 + idx];
      float w0 = consL[1536 + idx], w1w = consL[1664 + idx],
            w2w = consL[1792 + idx], w3w = consL[1920 + idx];
      {
        float ig = fsigm(b0 + x0 * w0), fg = fsigm(b1v + x0 * w1w);
        float gg = ftanh(b2v + x0 * w2w), og = fsigm(b3v + x0 * w3w);
        (void)fg; c1a = ig * gg; h1b[0][0][idx] = (f16)(og * ftanh(c1a));
      }
      {
        float ig = fsigm(b0 + x1 * w0), fg = fsigm(b1v + x1 * w1w);
        float gg = ftanh(b2v + x1 * w2w), og = fsigm(b3v + x1 * w3w);
        (void)fg; c1b = ig * gg; h1b[0][1][idx] = (f16)(og * ftanh(c1b));
      }
    }
    __syncthreads();
  }

  // ring prologue: loads c=0..7 (early chunk of step 0)
  uint4 ring[8];
#pragma unroll
  for (int c = 0; c < 8; ++c) ring[c] = W3p[c * 512];

  for (int s = 0; s < T_TOT; ++s) {
    const int par = s & 1;
    const int xi = (s + 1 < T_IN) ? (s + 1) : 0;
    float xl0 = input[row0 * T_IN + xi];
    float xl1 = input[row1 * T_IN + xi];

    const uint4* hL2r0 = (kq < 2)
        ? (const uint4*)&h1b[par][0][0] + kq * 8
        : (const uint4*)&h2b[par ^ 1][0][0] + (kq - 2) * 8;
    const uint4* hL2r1 = (kq < 2)
        ? (const uint4*)&h1b[par][1][0] + kq * 8
        : (const uint4*)&h2b[par ^ 1][1][0] + (kq - 2) * 8;
    const uint4* h3r0 = (const uint4*)&h3b[0][0] + kq * 4;
    const uint4* h3r1 = (const uint4*)&h3b[1][0] + kq * 4;

    float a2r0[4] = {0, 0, 0, 0}, a2r1[4] = {0, 0, 0, 0};
    float a3r0[4] = {0, 0, 0, 0}, a3r1[4] = {0, 0, 0, 0};

    // ---- P_A: L2 dots (32 u4) + L3-early dots (16 u4, ring) ----
    uint4 E0, E1;
#pragma unroll
    for (int q = 0; q < 8; ++q) {
      uint4 H0 = hL2r0[q], H1 = hL2r1[q];
      u32 e0[4] = {H0.x, H0.y, H0.z, H0.w};
      u32 e1[4] = {H1.x, H1.y, H1.z, H1.w};
#pragma unroll
      for (int e = 0; e < 4; ++e) {
        uint4 w = w2r[q * 4 + e];
        DOT4(a2r0, w, e0[e]);
        DOT4(a2r1, w, e1[e]);
      }
      if ((q & 1) == 0) { E0 = h3r0[q >> 1]; E1 = h3r1[q >> 1]; }
      {
        uint4 w = ring[(2 * q) & 7];
        ring[(2 * q) & 7] = W3p[(2 * q + 8) * 512];
        u32 h0 = (q & 1) ? E0.z : E0.x, h1v = (q & 1) ? E1.z : E1.x;
        DOT4(a3r0, w, h0);
        DOT4(a3r1, w, h1v);
      }
      {
        uint4 w = ring[(2 * q + 1) & 7];
        ring[(2 * q + 1) & 7] = W3p[(2 * q + 9) * 512];
        u32 h0 = (q & 1) ? E0.w : E0.y, h1v = (q & 1) ? E1.w : E1.y;
        DOT4(a3r0, w, h0);
        DOT4(a3r1, w, h1v);
      }
    }

    // L2 finish
#pragma unroll
    for (int g = 0; g < 4; ++g) {
      a2r0[g] += __shfl_xor(a2r0[g], 1, 64); a2r0[g] += __shfl_xor(a2r0[g], 2, 64);
      a2r1[g] += __shfl_xor(a2r1[g], 1, 64); a2r1[g] += __shfl_xor(a2r1[g], 2, 64);
    }
    if (kq == 0) {
      float b0 = consL[512 + idx], b1v = consL[640 + idx],
            b2v = consL[768 + idx], b3v = consL[896 + idx];
      {
        float ig = fsigm(a2r0[0] + b0), fg = fsigm(a2r0[1] + b1v);
        float gg = ftanh(a2r0[2] + b2v), og = fsigm(a2r0[3] + b3v);
        c2a = fg * c2a + ig * gg;
        h2b[par][0][idx] = (f16)(og * ftanh(c2a));
      }
      {
        float ig = fsigm(a2r1[0] + b0), fg = fsigm(a2r1[1] + b1v);
        float gg = ftanh(a2r1[2] + b2v), og = fsigm(a2r1[3] + b3v);
        c2b = fg * c2b + ig * gg;
        h2b[par][1][idx] = (f16)(og * ftanh(c2b));
      }
    }
    asm volatile("s_waitcnt lgkmcnt(0)\n\ts_barrier" ::: "memory");  // barrier1

    // ---- P_B: L3-late dots (16 u4, ring) + L1 dots for step s+1 (16 u4) ----
    const uint4* hLTr0 = (const uint4*)&h2b[par][0][0] + kq * 4;
    const uint4* hLTr1 = (const uint4*)&h2b[par][1][0] + kq * 4;
    const uint4* h1r0 = (const uint4*)&h1b[par][0][0] + kq * 4;
    const uint4* h1r1 = (const uint4*)&h1b[par][1][0] + kq * 4;

    float a1r0[4] = {0, 0, 0, 0}, a1r1[4] = {0, 0, 0, 0};
    uint4 L0, L1v, F0, F1;
#pragma unroll
    for (int q = 0; q < 8; ++q) {
      if ((q & 1) == 0) {
        L0 = hLTr0[q >> 1]; L1v = hLTr1[q >> 1];
        F0 = h1r0[q >> 1];  F1 = h1r1[q >> 1];
      }
      {
        uint4 w = ring[(2 * q) & 7];
        ring[(2 * q) & 7] = W3p[(((16 + 2 * q) + 8) & 31) * 512];
        u32 h0 = (q & 1) ? L0.z : L0.x, h1x = (q & 1) ? L1v.z : L1v.x;
        DOT4(a3r0, w, h0);
        DOT4(a3r1, w, h1x);
      }
      {
        uint4 w = ring[(2 * q + 1) & 7];
        ring[(2 * q + 1) & 7] = W3p[(((17 + 2 * q) + 8) & 31) * 512];
        u32 h0 = (q & 1) ? L0.w : L0.y, h1x = (q & 1) ? L1v.w : L1v.y;
        DOT4(a3r0, w, h0);
        DOT4(a3r1, w, h1x);
      }
      {
        uint4 w = w1p[(2 * q) * 128];
        u32 h0 = (q & 1) ? F0.z : F0.x, h1x = (q & 1) ? F1.z : F1.x;
        DOT4(a1r0, w, h0);
        DOT4(a1r1, w, h1x);
      }
      {
        uint4 w = w1p[(2 * q + 1) * 128];
        u32 h0 = (q & 1) ? F0.w : F0.y, h1x = (q & 1) ? F1.w : F1.y;
        DOT4(a1r0, w, h0);
        DOT4(a1r1, w, h1x);
      }
    }

#pragma unroll
    for (int g = 0; g < 4; ++g) {
      a3r0[g] += __shfl_xor(a3r0[g], 1, 64); a3r0[g] += __shfl_xor(a3r0[g], 2, 64);
      a3r1[g] += __shfl_xor(a3r1[g], 1, 64); a3r1[g] += __shfl_xor(a3r1[g], 2, 64);
      a1r0[g] += __shfl_xor(a1r0[g], 1, 64); a1r0[g] += __shfl_xor(a1r0[g], 2, 64);
      a1r1[g] += __shfl_xor(a1r1[g], 1, 64); a1r1[g] += __shfl_xor(a1r1[g], 2, 64);
    }

    // L3 finish + head partial
    float p0 = 0.f, p1 = 0.f;
    if (kq == 0) {
      float b0 = consL[1024 + idx], b1v = consL[1152 + idx],
            b2v = consL[1280 + idx], b3v = consL[1408 + idx];
      float weffr = consL[2048 + idx];
      {
        float ig = fsigm(a3r0[0] + b0), fg = fsigm(a3r0[1] + b1v);
        float gg = ftanh(a3r0[2] + b2v), og = fsigm(a3r0[3] + b3v);
        c3a = fg * c3a + ig * gg;
        float h3 = og * ftanh(c3a);
        h3b[0][idx] = (f16)h3;
        p0 = weffr * h3;
      }
      {
        float ig = fsigm(a3r1[0] + b0), fg = fsigm(a3r1[1] + b1v);
        float gg = ftanh(a3r1[2] + b2v), og = fsigm(a3r1[3] + b3v);
        c3b = fg * c3b + ig * gg;
        float h3 = og * ftanh(c3b);
        h3b[1][idx] = (f16)h3;
        p1 = weffr * h3;
      }
    }
#pragma unroll
    for (int k = 1; k < 64; k <<= 1) {
      p0 += __shfl_xor(p0, k, 64);
      p1 += __shfl_xor(p1, k, 64);
    }
    if ((t & 63) == 0) { redp[0][t >> 6] = p0; redp[1][t >> 6] = p1; }
    asm volatile("s_waitcnt lgkmcnt(0)\n\ts_barrier" ::: "memory");  // barrier2

    y0 = beffv; y1 = beffv;
#pragma unroll
    for (int w8 = 0; w8 < 8; ++w8) { y0 += redp[0][w8]; y1 += redp[1][w8]; }
    if (t == 0) out[row0 * T_TOT + s] = y0;
    else if (t == 1) out[row1 * T_TOT + s] = y1;

    // L1 finish for step s+1
    float xv0 = (s + 1 < T_IN) ? xl0 : y0;
    float xv1 = (s + 1 < T_IN) ? xl1 : y1;
    if (kq == 0) {
      float b0 = consL[idx], b1v = consL[128 + idx], b2v = consL[256 + idx],
            b3v = consL[384 + idx];
      float w0 = consL[1536 + idx], w1w = consL[1664 + idx],
            w2w = consL[1792 + idx], w3w = consL[1920 + idx];
      {
        float ig = fsigm(a1r0[0] + b0 + xv0 * w0), fg = fsigm(a1r0[1] + b1v + xv0 * w1w);
        float gg = ftanh(a1r0[2] + b2v + xv0 * w2w), og = fsigm(a1r0[3] + b3v + xv0 * w3w);
        c1a = fg * c1a + ig * gg;
        h1b[par ^ 1][0][idx] = (f16)(og * ftanh(c1a));
      }
      {
        float ig = fsigm(a1r1[0] + b0 + xv1 * w0), fg = fsigm(a1r1[1] + b1v + xv1 * w1w);
        float gg = ftanh(a1r1[2] + b2v + xv1 * w2w), og = fsigm(a1r1[3] + b3v + xv1 * w3w);
        c1b = fg * c1b + ig * gg;
        h1b[par ^ 1][1][idx] = (f16)(og * ftanh(c1b));
      }
    }
    asm volatile("s_waitcnt lgkmcnt(0)\n\ts_barrier" ::: "memory");  // barrier3
  }
}

// ---- launch ---------------------------------------------------------------
extern "C" void kernel_launch(void* const* d_in, const int* in_sizes, int n_in,
                              void* d_out, int out_size, void* d_ws, size_t ws_size,
                              hipStream_t stream) {
  const float* input = (const float*)d_in[0];
  const float* Wih1 = (const float*)d_in[2];
  const float* Whh1 = (const float*)d_in[3];
  const float* bih1 = (const float*)d_in[4];
  const float* bhh1 = (const float*)d_in[5];
  const float* Wih2 = (const float*)d_in[6];
  const float* Whh2 = (const float*)d_in[7];
  const float* bih2 = (const float*)d_in[8];
  const float* bhh2 = (const float*)d_in[9];
  const float* Wih3 = (const float*)d_in[10];
  const float* Whh3 = (const float*)d_in[11];
  const float* bih3 = (const float*)d_in[12];
  const float* bhh3 = (const float*)d_in[13];
  const float* in_proj_w = (const float*)d_in[14];
  const float* in_proj_b = (const float*)d_in[15];
  const float* out_w = (const float*)d_in[16];
  const float* out_b = (const float*)d_in[17];
  const float* lin_w = (const float*)d_in[18];
  const float* lin_b = (const float*)d_in[19];

  char* ws = (char*)d_ws;
  u32* WT1 = (u32*)(ws + (0 << 10));    // 128 KB swizzled L1
  u32* WT2 = (u32*)(ws + (128 << 10));  // 256 KB std L2
  u32* WT3r = (u32*)(ws + (384 << 10)); // 256 KB stream-ordered L3
  float* consG = (float*)(ws + (640 << 10)); // ~8.7 KB

  pack1<<<128, 256, 0, stream>>>(WT1, Whh1);
  pack_cat<<<256, 256, 0, stream>>>(WT2, Wih2, Whh2, 64, 128);
  pack3<<<256, 256, 0, stream>>>(WT3r, Wih3, Whh3);
  prep_cons<<<8, 256, 0, stream>>>(consG, bih1, bhh1, bih2, bhh2, bih3, bhh3, Wih1);
  head_fold<<<1, 128, 0, stream>>>(consG, lin_w, out_w,
                                   in_proj_w + 2 * 128 * 128, in_proj_b + 256,
                                   out_b, lin_b);

  pendulum_persist<<<NBLK, 512, 0, stream>>>(
      input, (const uint4*)WT1, (const uint4*)WT2, (const uint4*)WT3r,
      consG, (float*)d_out);
}